// Round 7
// baseline (290.676 us; speedup 1.0000x reference)
//
#include <hip/hip_runtime.h>

typedef __bf16 bf16;
typedef __bf16 bf16x8 __attribute__((ext_vector_type(8)));
typedef __bf16 bf16x4 __attribute__((ext_vector_type(4)));
typedef float f32x4 __attribute__((ext_vector_type(4)));

#define NB 2
#define NQ 2048
#define NKK 2048
#define NC 512
#define NH 8
#define ND 64
#define NM (NB*NQ)   // 4096 rows
#define SPLITS 4
#define KSPL (NKK/SPLITS)   // 512 k per split
#define NTILES (KSPL/32)    // 16 tiles of 32 k
#define PLS 40               // pl row stride (bf16): 80B rows -> 2-way banks (free), 16B-aligned b128 reads

// ---------------- pass 0a: f32 -> bf16 ----------------
__global__ __launch_bounds__(256) void cvt_bf16_kernel(const float* __restrict__ in,
                                                       bf16* __restrict__ out, int n4) {
  int i = blockIdx.x * 256 + threadIdx.x;
  if (i < n4) {
    float4 v = ((const float4*)in)[i];
    bf16x4 o;
    o[0] = (bf16)v.x; o[1] = (bf16)v.y; o[2] = (bf16)v.z; o[3] = (bf16)v.w;
    ((bf16x4*)out)[i] = o;
  }
}

// ---------------- pass 0b: W[512][512] f32 -> WT[n][k] bf16 ----------------
__global__ __launch_bounds__(256) void transpose_w_kernel(const float* __restrict__ W,
                                                          bf16* __restrict__ WT) {
  __shared__ float t[32][33];
  int n0 = blockIdx.x * 32, k0 = blockIdx.y * 32;
  int c = threadIdx.x & 31, r0 = threadIdx.x >> 5;
  for (int r = r0; r < 32; r += 8) t[r][c] = W[(size_t)(k0 + r) * NC + n0 + c];
  __syncthreads();
  for (int r = r0; r < 32; r += 8) WT[(size_t)(n0 + r) * NC + k0 + c] = (bf16)t[c][r];
}

// ---------------- pass 1/3: GEMM  Y[M][512] = X[M][512] @ WT^T, fused epilogues ----------------
// epi: 0=Q (scale 1/8 -> qh[b][h][q][d])  1=K -> kh  2=V -> vh  3=G (sigmoid+bg -> f32)  4=O (+bo -> f32 d_out)
__global__ __launch_bounds__(256) void gemm_kernel(const bf16* __restrict__ X,
                                                   const bf16* __restrict__ WT,
                                                   const float* __restrict__ bias,
                                                   void* __restrict__ out, int epi) {
  __shared__ bf16 Xs[64][72];
  __shared__ bf16 Ws[64][72];
  int m0 = blockIdx.y * 64, n0 = blockIdx.x * 64;
  int tid = threadIdx.x, lane = tid & 63, wave = tid >> 6;
  int wm = wave >> 1, wn = wave & 1;
  int lr = lane & 15, lg = lane >> 4;
  f32x4 acc[2][2] = {};
  for (int k0 = 0; k0 < 512; k0 += 64) {
#pragma unroll
    for (int j = 0; j < 2; j++) {
      int cc = tid + 256 * j;
      int r = cc >> 3, c8 = (cc & 7) * 8;
      *(uint4*)&Xs[r][c8] = *(const uint4*)&X[(size_t)(m0 + r) * 512 + k0 + c8];
      *(uint4*)&Ws[r][c8] = *(const uint4*)&WT[(size_t)(n0 + r) * 512 + k0 + c8];
    }
    __syncthreads();
#pragma unroll
    for (int kk = 0; kk < 64; kk += 32) {
      bf16x8 a[2], b[2];
      a[0] = *(const bf16x8*)&Xs[wm * 32 + lr][kk + lg * 8];
      a[1] = *(const bf16x8*)&Xs[wm * 32 + 16 + lr][kk + lg * 8];
      b[0] = *(const bf16x8*)&Ws[wn * 32 + lr][kk + lg * 8];
      b[1] = *(const bf16x8*)&Ws[wn * 32 + 16 + lr][kk + lg * 8];
#pragma unroll
      for (int mi = 0; mi < 2; mi++)
#pragma unroll
        for (int ni = 0; ni < 2; ni++)
          acc[mi][ni] = __builtin_amdgcn_mfma_f32_16x16x32_bf16(a[mi], b[ni], acc[mi][ni], 0, 0, 0);
    }
    __syncthreads();
  }
#pragma unroll
  for (int mi = 0; mi < 2; mi++) {
#pragma unroll
    for (int ni = 0; ni < 2; ni++) {
#pragma unroll
      for (int i = 0; i < 4; i++) {
        int grow = m0 + wm * 32 + mi * 16 + lg * 4 + i;
        int gcol = n0 + wn * 32 + ni * 16 + lr;
        float v = acc[mi][ni][i];
        if (epi == 0) {
          int b = grow >> 11, q = grow & 2047, h = gcol >> 6, d = gcol & 63;
          ((bf16*)out)[((size_t)(b * NH + h) * NQ + q) * ND + d] = (bf16)(v * 0.125f);
        } else if (epi == 1 || epi == 2) {
          int b = grow >> 11, kq = grow & 2047, h = gcol >> 6, d = gcol & 63;
          ((bf16*)out)[((size_t)(b * NH + h) * NKK + kq) * ND + d] = (bf16)v;
        } else if (epi == 3) {
          v += bias[gcol];
          v = 1.0f / (1.0f + __expf(-v));
          ((float*)out)[(size_t)grow * 512 + gcol] = v;
        } else {
          ((float*)out)[(size_t)grow * 512 + gcol] = v + bias[gcol];
        }
      }
    }
  }
}

// ---------------- pass 1.5: vh[b][h][k][d] -> vT[b][h][d][k] ----------------
__global__ __launch_bounds__(256) void transpose_v_kernel(const bf16* __restrict__ vh,
                                                          bf16* __restrict__ vT) {
  __shared__ bf16 t[64][72];
  int bh = blockIdx.y;
  int kk0 = blockIdx.x * 64;
  const bf16* src = vh + (size_t)bh * NKK * ND;
  bf16* dst = vT + (size_t)bh * ND * NKK;
#pragma unroll
  for (int j = 0; j < 2; j++) {
    int c = threadIdx.x + 256 * j;
    int r = c >> 3, cc = (c & 7) * 8;
    *(uint4*)&t[r][cc] = *(const uint4*)&src[(size_t)(kk0 + r) * ND + cc];
  }
  __syncthreads();
#pragma unroll
  for (int j = 0; j < 2; j++) {
    int c = threadIdx.x + 256 * j;
    int d = c >> 3, ck = (c & 7) * 8;
    bf16 tmp[8];
#pragma unroll
    for (int x = 0; x < 8; x++) tmp[x] = t[ck + x][d];
    *(uint4*)&dst[(size_t)d * NKK + kk0 + ck] = *(const uint4*)tmp;
  }
}

// ---------------- pass 2: fused flash attention ----------------
// S^T form: sT = mfma(kf, qf) so C-rows = k (contiguous in bias memory) ->
// bias loads are float4 landing exactly on the C fragment. 12 VMEM/tile.
// grid (512): XCD-swizzled (q-tile, split); 16 waves = (b,h) pairs.
__global__ __launch_bounds__(1024, 4) void attn_kernel(
    const bf16* __restrict__ qh, const bf16* __restrict__ kh, const bf16* __restrict__ vT,
    const float* __restrict__ bias1, const float* __restrict__ bias2,
    float* __restrict__ o_part, float* __restrict__ l_part) {
  __shared__ bf16 plds[16][16][PLS];
  int l = blockIdx.x;
  int swz = (l & 7) * 64 + (l >> 3);
  int q0 = (swz & 127) * 16;
  int split = swz >> 7;
  int w = threadIdx.x >> 6, lane = threadIdx.x & 63;
  int b = w >> 3, h = w & 7;
  int lr = lane & 15, lg = lane >> 4;
  int kbase = split * KSPL;
  const bf16* Qp = qh + ((size_t)(b * NH + h) * NQ + q0) * ND;
  const bf16* Kp = kh + (size_t)(b * NH + h) * NKK * ND + (size_t)kbase * ND;
  const bf16* Vt = vT + (size_t)(b * NH + h) * ND * NKK + kbase;
  // per-lane bias row pointers (row = q0+lr), at column kbase
  const float* b1p = bias1 + ((size_t)b * NQ + q0 + lr) * NKK + kbase + lg * 4;
  const float* b2p = bias2 + ((size_t)h * NQ + q0 + lr) * NKK + kbase + lg * 4;

  bf16x8 qf0 = *(const bf16x8*)&Qp[lr * 64 + lg * 8];
  bf16x8 qf1 = *(const bf16x8*)&Qp[lr * 64 + 32 + lg * 8];

  f32x4 o[4] = {};
  float lsum = 0.f;
  bf16(*pl)[PLS] = plds[w];

  // 2-deep software pipeline on the (HBM-latency) bias loads only; K/V come from L2.
  f32x4 b1A0, b1A1, b2A0, b2A1, b1B0, b1B1, b2B0, b2B1;

#define LOAD_BIAS(kt, b1lo, b1hi, b2lo, b2hi)              \
  do {                                                     \
    const float* p1 = b1p + (kt) * 32;                     \
    const float* p2 = b2p + (kt) * 32;                     \
    b1lo = *(const f32x4*)p1;  b1hi = *(const f32x4*)(p1 + 16); \
    b2lo = *(const f32x4*)p2;  b2hi = *(const f32x4*)(p2 + 16); \
  } while (0)

#define COMPUTE(kt, b1lo, b1hi, b2lo, b2hi)                                        \
  do {                                                                             \
    const bf16* kp = Kp + (size_t)((kt) * 32 + lr) * ND + lg * 8;                  \
    bf16x8 kf00 = *(const bf16x8*)kp;                                              \
    bf16x8 kf01 = *(const bf16x8*)(kp + 32);                                       \
    bf16x8 kf10 = *(const bf16x8*)(kp + 16 * ND);                                  \
    bf16x8 kf11 = *(const bf16x8*)(kp + 16 * ND + 32);                             \
    bf16x8 vf0 = *(const bf16x8*)&Vt[(size_t)(0 * 16 + lr) * NKK + (kt) * 32 + lg * 8]; \
    bf16x8 vf1 = *(const bf16x8*)&Vt[(size_t)(1 * 16 + lr) * NKK + (kt) * 32 + lg * 8]; \
    bf16x8 vf2 = *(const bf16x8*)&Vt[(size_t)(2 * 16 + lr) * NKK + (kt) * 32 + lg * 8]; \
    bf16x8 vf3 = *(const bf16x8*)&Vt[(size_t)(3 * 16 + lr) * NKK + (kt) * 32 + lg * 8]; \
    f32x4 c0 = {}, c1 = {};                                                        \
    c0 = __builtin_amdgcn_mfma_f32_16x16x32_bf16(kf00, qf0, c0, 0, 0, 0);          \
    c0 = __builtin_amdgcn_mfma_f32_16x16x32_bf16(kf01, qf1, c0, 0, 0, 0);          \
    c1 = __builtin_amdgcn_mfma_f32_16x16x32_bf16(kf10, qf0, c1, 0, 0, 0);          \
    c1 = __builtin_amdgcn_mfma_f32_16x16x32_bf16(kf11, qf1, c1, 0, 0, 0);          \
    bf16x4 pk0, pk1;                                                               \
    _Pragma("unroll")                                                              \
    for (int i = 0; i < 4; i++) {                                                  \
      float p0 = __expf(c0[i] + b1lo[i] + b2lo[i]);                                \
      float p1v = __expf(c1[i] + b1hi[i] + b2hi[i]);                               \
      lsum += p0 + p1v;                                                            \
      pk0[i] = (bf16)p0;  pk1[i] = (bf16)p1v;                                      \
    }                                                                              \
    *(bf16x4*)&pl[lr][lg * 4] = pk0;                                               \
    *(bf16x4*)&pl[lr][16 + lg * 4] = pk1;                                          \
    bf16x8 pa = *(const bf16x8*)&pl[lr][lg * 8];                                   \
    o[0] = __builtin_amdgcn_mfma_f32_16x16x32_bf16(pa, vf0, o[0], 0, 0, 0);        \
    o[1] = __builtin_amdgcn_mfma_f32_16x16x32_bf16(pa, vf1, o[1], 0, 0, 0);        \
    o[2] = __builtin_amdgcn_mfma_f32_16x16x32_bf16(pa, vf2, o[2], 0, 0, 0);        \
    o[3] = __builtin_amdgcn_mfma_f32_16x16x32_bf16(pa, vf3, o[3], 0, 0, 0);        \
  } while (0)

  LOAD_BIAS(0, b1A0, b1A1, b2A0, b2A1);
#pragma unroll
  for (int t = 0; t < NTILES; t += 2) {
    LOAD_BIAS(t + 1, b1B0, b1B1, b2B0, b2B1);
    COMPUTE(t, b1A0, b1A1, b2A0, b2A1);
    if (t + 2 < NTILES) LOAD_BIAS(t + 2, b1A0, b1A1, b2A0, b2A1);
    COMPUTE(t + 1, b1B0, b1B1, b2B0, b2B1);
  }
#undef LOAD_BIAS
#undef COMPUTE

  // full row-sum for q = lr: reduce across the 4 lg groups (lane bits 4-5)
  float L = lsum;
  L += __shfl_xor(L, 16);
  L += __shfl_xor(L, 32);

  float* op = o_part + (((size_t)(split * NB + b) * NH + h) * NQ + q0) * ND;
#pragma unroll
  for (int ni = 0; ni < 4; ni++)
#pragma unroll
    for (int i = 0; i < 4; i++)
      op[(lg * 4 + i) * ND + ni * 16 + lr] = o[ni][i];
  if (lg == 0) {
    float* lp = l_part + ((size_t)(split * NB + b) * NH + h) * NQ + q0;
    lp[lr] = L;
  }
}

// ---------------- pass 2b: combine splits, gate, -> bf16 ----------------
__global__ __launch_bounds__(256) void combine_kernel(const float* __restrict__ o_part,
                                                      const float* __restrict__ l_part,
                                                      const float* __restrict__ gate,
                                                      bf16* __restrict__ ao) {
  size_t t = (size_t)blockIdx.x * 256 + threadIdx.x;  // over B*Q*H*16
  int d0 = (int)(t & 15) * 4;
  int h = (int)((t >> 4) & 7);
  int q = (int)((t >> 7) & 2047);
  int b = (int)(t >> 18);
  f32x4 acc = {};
  float L = 0.f;
#pragma unroll
  for (int s = 0; s < SPLITS; s++) {
    size_t base = (((size_t)(s * NB + b) * NH + h) * NQ + q);
    acc += *(const f32x4*)&o_part[base * ND + d0];
    L += l_part[base];
  }
  float inv = 1.0f / L;
  size_t gi = ((size_t)b * NQ + q) * 512 + h * 64 + d0;
  f32x4 g = *(const f32x4*)&gate[gi];
  bf16x4 r;
#pragma unroll
  for (int j = 0; j < 4; j++) r[j] = (bf16)(acc[j] * inv * g[j]);
  *(bf16x4*)&ao[gi] = r;
}

// ---------------- host launch ----------------
extern "C" void kernel_launch(void* const* d_in, const int* in_sizes, int n_in,
                              void* d_out, int out_size, void* d_ws, size_t ws_size,
                              hipStream_t stream) {
  const float* query = (const float*)d_in[0];
  const float* keyd  = (const float*)d_in[1];
  const float* bias1 = (const float*)d_in[2];
  const float* bias2 = (const float*)d_in[3];
  const float* wq = (const float*)d_in[4];
  const float* wk = (const float*)d_in[5];
  const float* wv = (const float*)d_in[6];
  const float* wo = (const float*)d_in[7];
  const float* bo = (const float*)d_in[8];
  const float* wg = (const float*)d_in[9];
  const float* bg = (const float*)d_in[10];

  char* ws = (char*)d_ws;
  size_t off = 0;
  auto alloc = [&](size_t bytes) {
    void* p = ws + off;
    off += (bytes + 255) & ~(size_t)255;
    return p;
  };
  bf16* qd_bf = (bf16*)alloc((size_t)NM * 512 * 2);
  bf16* kd_bf = (bf16*)alloc((size_t)NM * 512 * 2);
  bf16* wqT = (bf16*)alloc((size_t)512 * 512 * 2);
  bf16* wkT = (bf16*)alloc((size_t)512 * 512 * 2);
  bf16* wvT = (bf16*)alloc((size_t)512 * 512 * 2);
  bf16* wgT = (bf16*)alloc((size_t)512 * 512 * 2);
  bf16* woT = (bf16*)alloc((size_t)512 * 512 * 2);
  bf16* qh  = (bf16*)alloc((size_t)NB * NH * NQ * ND * 2);
  bf16* kh  = (bf16*)alloc((size_t)NB * NH * NKK * ND * 2);
  bf16* vh  = (bf16*)alloc((size_t)NB * NH * NKK * ND * 2);
  bf16* vTt = (bf16*)alloc((size_t)NB * NH * ND * NKK * 2);
  float* gbuf = (float*)alloc((size_t)NM * 512 * 4);
  bf16* aob = (bf16*)alloc((size_t)NM * 512 * 2);
  float* o_part = (float*)alloc((size_t)SPLITS * NB * NH * NQ * ND * 4);
  float* l_part = (float*)alloc((size_t)SPLITS * NB * NH * NQ * 4);

  int n4 = NM * 512 / 4;
  cvt_bf16_kernel<<<dim3(n4 / 256), 256, 0, stream>>>(query, qd_bf, n4);
  cvt_bf16_kernel<<<dim3(n4 / 256), 256, 0, stream>>>(keyd, kd_bf, n4);

  transpose_w_kernel<<<dim3(16, 16), 256, 0, stream>>>(wq, wqT);
  transpose_w_kernel<<<dim3(16, 16), 256, 0, stream>>>(wk, wkT);
  transpose_w_kernel<<<dim3(16, 16), 256, 0, stream>>>(wv, wvT);
  transpose_w_kernel<<<dim3(16, 16), 256, 0, stream>>>(wg, wgT);
  transpose_w_kernel<<<dim3(16, 16), 256, 0, stream>>>(wo, woT);

  gemm_kernel<<<dim3(8, 64), 256, 0, stream>>>(qd_bf, wqT, nullptr, qh, 0);
  gemm_kernel<<<dim3(8, 64), 256, 0, stream>>>(kd_bf, wkT, nullptr, kh, 1);
  gemm_kernel<<<dim3(8, 64), 256, 0, stream>>>(kd_bf, wvT, nullptr, vh, 2);
  gemm_kernel<<<dim3(8, 64), 256, 0, stream>>>(qd_bf, wgT, bg, gbuf, 3);

  transpose_v_kernel<<<dim3(32, 16), 256, 0, stream>>>(vh, vTt);

  attn_kernel<<<dim3(512), 1024, 0, stream>>>(qh, kh, vTt, bias1, bias2, o_part, l_part);

  combine_kernel<<<dim3((NB * NQ * NH * 16) / 256), 256, 0, stream>>>(o_part, l_part, gbuf, aob);

  gemm_kernel<<<dim3(8, 64), 256, 0, stream>>>(aob, woT, bo, d_out, 4);
}

// Round 8
// 262.161 us; speedup vs baseline: 1.1088x; 1.1088x over previous
//
#include <hip/hip_runtime.h>

typedef __bf16 bf16;
typedef __bf16 bf16x8 __attribute__((ext_vector_type(8)));
typedef __bf16 bf16x4 __attribute__((ext_vector_type(4)));
typedef float f32x4 __attribute__((ext_vector_type(4)));

#define NB 2
#define NQ 2048
#define NKK 2048
#define NC 512
#define NH 8
#define ND 64
#define NM (NB*NQ)   // 4096 rows
#define SPLITS 4
#define KSPL (NKK/SPLITS)   // 512 k per split
#define NTILES (KSPL/32)    // 16 tiles of 32 k
#define PLS 36              // proven 0-conflict stride

// ---------------- pass 0a: f32 -> bf16 ----------------
__global__ __launch_bounds__(256) void cvt_bf16_kernel(const float* __restrict__ in,
                                                       bf16* __restrict__ out, int n4) {
  int i = blockIdx.x * 256 + threadIdx.x;
  if (i < n4) {
    float4 v = ((const float4*)in)[i];
    bf16x4 o;
    o[0] = (bf16)v.x; o[1] = (bf16)v.y; o[2] = (bf16)v.z; o[3] = (bf16)v.w;
    ((bf16x4*)out)[i] = o;
  }
}

// ---------------- pass 0b: W[512][512] f32 -> WT[n][k] bf16 ----------------
__global__ __launch_bounds__(256) void transpose_w_kernel(const float* __restrict__ W,
                                                          bf16* __restrict__ WT) {
  __shared__ float t[32][33];
  int n0 = blockIdx.x * 32, k0 = blockIdx.y * 32;
  int c = threadIdx.x & 31, r0 = threadIdx.x >> 5;
  for (int r = r0; r < 32; r += 8) t[r][c] = W[(size_t)(k0 + r) * NC + n0 + c];
  __syncthreads();
  for (int r = r0; r < 32; r += 8) WT[(size_t)(n0 + r) * NC + k0 + c] = (bf16)t[c][r];
}

// ---------------- pass 1/3: GEMM  Y[M][512] = X[M][512] @ WT^T, fused epilogues ----------------
// epi: 0=Q (scale 1/8 -> qh[b][h][q][d])  1=K -> kh  2=V -> vh  3=G (sigmoid+bg -> f32)  4=O (+bo -> f32 d_out)
__global__ __launch_bounds__(256) void gemm_kernel(const bf16* __restrict__ X,
                                                   const bf16* __restrict__ WT,
                                                   const float* __restrict__ bias,
                                                   void* __restrict__ out, int epi) {
  __shared__ bf16 Xs[64][72];
  __shared__ bf16 Ws[64][72];
  int m0 = blockIdx.y * 64, n0 = blockIdx.x * 64;
  int tid = threadIdx.x, lane = tid & 63, wave = tid >> 6;
  int wm = wave >> 1, wn = wave & 1;
  int lr = lane & 15, lg = lane >> 4;
  f32x4 acc[2][2] = {};
  for (int k0 = 0; k0 < 512; k0 += 64) {
#pragma unroll
    for (int j = 0; j < 2; j++) {
      int cc = tid + 256 * j;
      int r = cc >> 3, c8 = (cc & 7) * 8;
      *(uint4*)&Xs[r][c8] = *(const uint4*)&X[(size_t)(m0 + r) * 512 + k0 + c8];
      *(uint4*)&Ws[r][c8] = *(const uint4*)&WT[(size_t)(n0 + r) * 512 + k0 + c8];
    }
    __syncthreads();
#pragma unroll
    for (int kk = 0; kk < 64; kk += 32) {
      bf16x8 a[2], b[2];
      a[0] = *(const bf16x8*)&Xs[wm * 32 + lr][kk + lg * 8];
      a[1] = *(const bf16x8*)&Xs[wm * 32 + 16 + lr][kk + lg * 8];
      b[0] = *(const bf16x8*)&Ws[wn * 32 + lr][kk + lg * 8];
      b[1] = *(const bf16x8*)&Ws[wn * 32 + 16 + lr][kk + lg * 8];
#pragma unroll
      for (int mi = 0; mi < 2; mi++)
#pragma unroll
        for (int ni = 0; ni < 2; ni++)
          acc[mi][ni] = __builtin_amdgcn_mfma_f32_16x16x32_bf16(a[mi], b[ni], acc[mi][ni], 0, 0, 0);
    }
    __syncthreads();
  }
#pragma unroll
  for (int mi = 0; mi < 2; mi++) {
#pragma unroll
    for (int ni = 0; ni < 2; ni++) {
#pragma unroll
      for (int i = 0; i < 4; i++) {
        int grow = m0 + wm * 32 + mi * 16 + lg * 4 + i;
        int gcol = n0 + wn * 32 + ni * 16 + lr;
        float v = acc[mi][ni][i];
        if (epi == 0) {
          int b = grow >> 11, q = grow & 2047, h = gcol >> 6, d = gcol & 63;
          ((bf16*)out)[((size_t)(b * NH + h) * NQ + q) * ND + d] = (bf16)(v * 0.125f);
        } else if (epi == 1 || epi == 2) {
          int b = grow >> 11, kq = grow & 2047, h = gcol >> 6, d = gcol & 63;
          ((bf16*)out)[((size_t)(b * NH + h) * NKK + kq) * ND + d] = (bf16)v;
        } else if (epi == 3) {
          v += bias[gcol];
          v = 1.0f / (1.0f + __expf(-v));
          ((float*)out)[(size_t)grow * 512 + gcol] = v;
        } else {
          ((float*)out)[(size_t)grow * 512 + gcol] = v + bias[gcol];
        }
      }
    }
  }
}

// ---------------- pass 1.5: vh[b][h][k][d] -> vT[b][h][d][k] ----------------
__global__ __launch_bounds__(256) void transpose_v_kernel(const bf16* __restrict__ vh,
                                                          bf16* __restrict__ vT) {
  __shared__ bf16 t[64][72];
  int bh = blockIdx.y;
  int kk0 = blockIdx.x * 64;
  const bf16* src = vh + (size_t)bh * NKK * ND;
  bf16* dst = vT + (size_t)bh * ND * NKK;
#pragma unroll
  for (int j = 0; j < 2; j++) {
    int c = threadIdx.x + 256 * j;
    int r = c >> 3, cc = (c & 7) * 8;
    *(uint4*)&t[r][cc] = *(const uint4*)&src[(size_t)(kk0 + r) * ND + cc];
  }
  __syncthreads();
#pragma unroll
  for (int j = 0; j < 2; j++) {
    int c = threadIdx.x + 256 * j;
    int d = c >> 3, ck = (c & 7) * 8;
    bf16 tmp[8];
#pragma unroll
    for (int x = 0; x < 8; x++) tmp[x] = t[ck + x][d];
    *(uint4*)&dst[(size_t)d * NKK + kk0 + ck] = *(const uint4*)tmp;
  }
}

// ---------------- pass 2: fused flash attention (R1 structure + K-split + no-max softmax) ----------------
// grid (128, 2, 4): x=q-tile, y=b, z=split; 8 waves = 8 heads (bias1 shared in-WG).
// Manual 2-deep prefetch of the HBM-latency streams (bias1/bias2/K); V loaded at
// compute start (L2-warm: reused by 128 q-tile WGs per (b,h,split)).
struct Tile {
  float b1v[2][4];
  float b2v[2][4];
  bf16x8 kf[2][2];
};

__device__ __forceinline__ void load_tile(int k0, const float* __restrict__ b1,
                                          const float* __restrict__ b2,
                                          const bf16* __restrict__ Kp,
                                          int lr, int lg, Tile& T) {
#pragma unroll
  for (int f = 0; f < 2; f++) {
#pragma unroll
    for (int i = 0; i < 4; i++) {
      int row = lg * 4 + i;
      int col = k0 + f * 16 + lr;
      T.b1v[f][i] = b1[row * NKK + col];
      T.b2v[f][i] = b2[row * NKK + col];
    }
  }
#pragma unroll
  for (int f = 0; f < 2; f++) {
#pragma unroll
    for (int kc = 0; kc < 2; kc++)
      T.kf[f][kc] = *(const bf16x8*)&Kp[(size_t)(k0 + f * 16 + lr) * ND + kc * 32 + lg * 8];
  }
}

__device__ __forceinline__ void compute_tile(const Tile& T, int k0,
                                             const bf16* __restrict__ Vt,
                                             bf16x8 qf0, bf16x8 qf1,
                                             f32x4 (&o)[4], float (&lrow)[4],
                                             bf16 (*pl)[PLS], int lr, int lg) {
  // V loads issued first: their L2 latency is covered by the QK MFMA + exp chain below
  bf16x8 vf0 = *(const bf16x8*)&Vt[(size_t)(0 * 16 + lr) * NKK + k0 + lg * 8];
  bf16x8 vf1 = *(const bf16x8*)&Vt[(size_t)(1 * 16 + lr) * NKK + k0 + lg * 8];
  bf16x8 vf2 = *(const bf16x8*)&Vt[(size_t)(2 * 16 + lr) * NKK + k0 + lg * 8];
  bf16x8 vf3 = *(const bf16x8*)&Vt[(size_t)(3 * 16 + lr) * NKK + k0 + lg * 8];
  f32x4 s[2];
#pragma unroll
  for (int f = 0; f < 2; f++) {
    f32x4 c;
#pragma unroll
    for (int i = 0; i < 4; i++) c[i] = T.b1v[f][i] + T.b2v[f][i];
    c = __builtin_amdgcn_mfma_f32_16x16x32_bf16(qf0, T.kf[f][0], c, 0, 0, 0);
    c = __builtin_amdgcn_mfma_f32_16x16x32_bf16(qf1, T.kf[f][1], c, 0, 0, 0);
    s[f] = c;
  }
  // p = exp(s); per-lane partial row sums (no max subtraction, no per-tile reduce)
#pragma unroll
  for (int i = 0; i < 4; i++) {
    float p0 = __expf(s[0][i]);
    float p1 = __expf(s[1][i]);
    lrow[i] += p0 + p1;
    pl[lg * 4 + i][lr] = (bf16)p0;
    pl[lg * 4 + i][16 + lr] = (bf16)p1;
  }
  bf16x8 pa = *(const bf16x8*)&pl[lr][lg * 8];
  o[0] = __builtin_amdgcn_mfma_f32_16x16x32_bf16(pa, vf0, o[0], 0, 0, 0);
  o[1] = __builtin_amdgcn_mfma_f32_16x16x32_bf16(pa, vf1, o[1], 0, 0, 0);
  o[2] = __builtin_amdgcn_mfma_f32_16x16x32_bf16(pa, vf2, o[2], 0, 0, 0);
  o[3] = __builtin_amdgcn_mfma_f32_16x16x32_bf16(pa, vf3, o[3], 0, 0, 0);
}

__global__ __launch_bounds__(512, 4) void attn_kernel(
    const bf16* __restrict__ qh, const bf16* __restrict__ kh, const bf16* __restrict__ vT,
    const float* __restrict__ bias1, const float* __restrict__ bias2,
    float* __restrict__ o_part, float* __restrict__ l_part) {
  __shared__ bf16 plds[8][16][PLS];
  int b = blockIdx.y, q0 = blockIdx.x * 16, split = blockIdx.z;
  int h = threadIdx.x >> 6, lane = threadIdx.x & 63;
  int lr = lane & 15, lg = lane >> 4;
  int kbase = split * KSPL;
  const bf16* Qp = qh + ((size_t)(b * NH + h) * NQ + q0) * ND;
  const bf16* Kp = kh + (size_t)(b * NH + h) * NKK * ND;
  const bf16* Vt = vT + (size_t)(b * NH + h) * ND * NKK;
  const float* b1 = bias1 + ((size_t)b * NQ + q0) * NKK;
  const float* b2 = bias2 + ((size_t)h * NQ + q0) * NKK;

  bf16x8 qf0 = *(const bf16x8*)&Qp[lr * 64 + lg * 8];
  bf16x8 qf1 = *(const bf16x8*)&Qp[lr * 64 + 32 + lg * 8];

  f32x4 o[4] = {};
  float lrow[4] = {0.f, 0.f, 0.f, 0.f};
  bf16(*pl)[PLS] = plds[h];

  Tile TA, TB;
  load_tile(kbase, b1, b2, Kp, lr, lg, TA);
  for (int t = 0; t < NTILES; t += 2) {
    load_tile(kbase + (t + 1) * 32, b1, b2, Kp, lr, lg, TB);
    compute_tile(TA, kbase + t * 32, Vt, qf0, qf1, o, lrow, pl, lr, lg);
    if (t + 2 < NTILES) load_tile(kbase + (t + 2) * 32, b1, b2, Kp, lr, lg, TA);
    compute_tile(TB, kbase + (t + 1) * 32, Vt, qf0, qf1, o, lrow, pl, lr, lg);
  }

  // final row-sum reduce over the 16 lanes holding this row's columns (lr bits only)
  float lred[4];
#pragma unroll
  for (int i = 0; i < 4; i++) {
    float L = lrow[i];
    L += __shfl_xor(L, 1);
    L += __shfl_xor(L, 2);
    L += __shfl_xor(L, 4);
    L += __shfl_xor(L, 8);
    lred[i] = L;
  }

  float* op = o_part + (((size_t)(split * NB + b) * NH + h) * NQ + q0) * ND;
#pragma unroll
  for (int ni = 0; ni < 4; ni++)
#pragma unroll
    for (int i = 0; i < 4; i++)
      op[(lg * 4 + i) * ND + ni * 16 + lr] = o[ni][i];
  if (lr == 0) {
    float* lp = l_part + ((size_t)(split * NB + b) * NH + h) * NQ + q0;
#pragma unroll
    for (int i = 0; i < 4; i++) lp[lg * 4 + i] = lred[i];
  }
}

// ---------------- pass 2b: combine splits, gate, -> bf16 ----------------
__global__ __launch_bounds__(256) void combine_kernel(const float* __restrict__ o_part,
                                                      const float* __restrict__ l_part,
                                                      const float* __restrict__ gate,
                                                      bf16* __restrict__ ao) {
  size_t t = (size_t)blockIdx.x * 256 + threadIdx.x;  // over B*Q*H*16
  int d0 = (int)(t & 15) * 4;
  int h = (int)((t >> 4) & 7);
  int q = (int)((t >> 7) & 2047);
  int b = (int)(t >> 18);
  f32x4 acc = {};
  float L = 0.f;
#pragma unroll
  for (int s = 0; s < SPLITS; s++) {
    size_t base = (((size_t)(s * NB + b) * NH + h) * NQ + q);
    acc += *(const f32x4*)&o_part[base * ND + d0];
    L += l_part[base];
  }
  float inv = 1.0f / L;
  size_t gi = ((size_t)b * NQ + q) * 512 + h * 64 + d0;
  f32x4 g = *(const f32x4*)&gate[gi];
  bf16x4 r;
#pragma unroll
  for (int j = 0; j < 4; j++) r[j] = (bf16)(acc[j] * inv * g[j]);
  *(bf16x4*)&ao[gi] = r;
}

// ---------------- host launch ----------------
extern "C" void kernel_launch(void* const* d_in, const int* in_sizes, int n_in,
                              void* d_out, int out_size, void* d_ws, size_t ws_size,
                              hipStream_t stream) {
  const float* query = (const float*)d_in[0];
  const float* keyd  = (const float*)d_in[1];
  const float* bias1 = (const float*)d_in[2];
  const float* bias2 = (const float*)d_in[3];
  const float* wq = (const float*)d_in[4];
  const float* wk = (const float*)d_in[5];
  const float* wv = (const float*)d_in[6];
  const float* wo = (const float*)d_in[7];
  const float* bo = (const float*)d_in[8];
  const float* wg = (const float*)d_in[9];
  const float* bg = (const float*)d_in[10];

  char* ws = (char*)d_ws;
  size_t off = 0;
  auto alloc = [&](size_t bytes) {
    void* p = ws + off;
    off += (bytes + 255) & ~(size_t)255;
    return p;
  };
  bf16* qd_bf = (bf16*)alloc((size_t)NM * 512 * 2);
  bf16* kd_bf = (bf16*)alloc((size_t)NM * 512 * 2);
  bf16* wqT = (bf16*)alloc((size_t)512 * 512 * 2);
  bf16* wkT = (bf16*)alloc((size_t)512 * 512 * 2);
  bf16* wvT = (bf16*)alloc((size_t)512 * 512 * 2);
  bf16* wgT = (bf16*)alloc((size_t)512 * 512 * 2);
  bf16* woT = (bf16*)alloc((size_t)512 * 512 * 2);
  bf16* qh  = (bf16*)alloc((size_t)NB * NH * NQ * ND * 2);
  bf16* kh  = (bf16*)alloc((size_t)NB * NH * NKK * ND * 2);
  bf16* vh  = (bf16*)alloc((size_t)NB * NH * NKK * ND * 2);
  bf16* vTt = (bf16*)alloc((size_t)NB * NH * ND * NKK * 2);
  float* gbuf = (float*)alloc((size_t)NM * 512 * 4);
  bf16* aob = (bf16*)alloc((size_t)NM * 512 * 2);
  float* o_part = (float*)alloc((size_t)SPLITS * NB * NH * NQ * ND * 4);
  float* l_part = (float*)alloc((size_t)SPLITS * NB * NH * NQ * 4);

  int n4 = NM * 512 / 4;
  cvt_bf16_kernel<<<dim3(n4 / 256), 256, 0, stream>>>(query, qd_bf, n4);
  cvt_bf16_kernel<<<dim3(n4 / 256), 256, 0, stream>>>(keyd, kd_bf, n4);

  transpose_w_kernel<<<dim3(16, 16), 256, 0, stream>>>(wq, wqT);
  transpose_w_kernel<<<dim3(16, 16), 256, 0, stream>>>(wk, wkT);
  transpose_w_kernel<<<dim3(16, 16), 256, 0, stream>>>(wv, wvT);
  transpose_w_kernel<<<dim3(16, 16), 256, 0, stream>>>(wg, wgT);
  transpose_w_kernel<<<dim3(16, 16), 256, 0, stream>>>(wo, woT);

  gemm_kernel<<<dim3(8, 64), 256, 0, stream>>>(qd_bf, wqT, nullptr, qh, 0);
  gemm_kernel<<<dim3(8, 64), 256, 0, stream>>>(kd_bf, wkT, nullptr, kh, 1);
  gemm_kernel<<<dim3(8, 64), 256, 0, stream>>>(kd_bf, wvT, nullptr, vh, 2);
  gemm_kernel<<<dim3(8, 64), 256, 0, stream>>>(qd_bf, wgT, bg, gbuf, 3);

  transpose_v_kernel<<<dim3(32, 16), 256, 0, stream>>>(vh, vTt);

  attn_kernel<<<dim3(128, 2, 4), 512, 0, stream>>>(qh, kh, vTt, bias1, bias2, o_part, l_part);

  combine_kernel<<<dim3((NB * NQ * NH * 16) / 256), 256, 0, stream>>>(o_part, l_part, gbuf, aob);

  gemm_kernel<<<dim3(8, 64), 256, 0, stream>>>(aob, woT, bo, d_out, 4);
}

// Round 9
// 253.016 us; speedup vs baseline: 1.1488x; 1.0361x over previous
//
#include <hip/hip_runtime.h>

typedef __bf16 bf16;
typedef __bf16 bf16x8 __attribute__((ext_vector_type(8)));
typedef __bf16 bf16x4 __attribute__((ext_vector_type(4)));
typedef float f32x4 __attribute__((ext_vector_type(4)));

#define NB 2
#define NQ 2048
#define NKK 2048
#define NC 512
#define NH 8
#define ND 64
#define NM (NB*NQ)   // 4096 rows
#define SPLITS 4
#define KSPL (NKK/SPLITS)   // 512 k per split
#define NTILES (KSPL/32)    // 16 chunks of 32 k
#define PLS 36              // proven 0-conflict stride

// ---------------- pass 0a: f32 -> bf16 ----------------
__global__ __launch_bounds__(256) void cvt_bf16_kernel(const float* __restrict__ in,
                                                       bf16* __restrict__ out, int n4) {
  int i = blockIdx.x * 256 + threadIdx.x;
  if (i < n4) {
    float4 v = ((const float4*)in)[i];
    bf16x4 o;
    o[0] = (bf16)v.x; o[1] = (bf16)v.y; o[2] = (bf16)v.z; o[3] = (bf16)v.w;
    ((bf16x4*)out)[i] = o;
  }
}

// ---------------- pass 0b: W[512][512] f32 -> WT[n][k] bf16 ----------------
__global__ __launch_bounds__(256) void transpose_w_kernel(const float* __restrict__ W,
                                                          bf16* __restrict__ WT) {
  __shared__ float t[32][33];
  int n0 = blockIdx.x * 32, k0 = blockIdx.y * 32;
  int c = threadIdx.x & 31, r0 = threadIdx.x >> 5;
  for (int r = r0; r < 32; r += 8) t[r][c] = W[(size_t)(k0 + r) * NC + n0 + c];
  __syncthreads();
  for (int r = r0; r < 32; r += 8) WT[(size_t)(n0 + r) * NC + k0 + c] = (bf16)t[c][r];
}

// ---------------- pass 1/3: GEMM  Y[M][512] = X[M][512] @ WT^T, fused epilogues ----------------
// epi: 0=Q (scale 1/8 -> qh[b][h][q][d])  1=K -> kh  2=V -> vh  3=G (sigmoid+bg -> f32)  4=O (+bo -> f32 d_out)
__global__ __launch_bounds__(256) void gemm_kernel(const bf16* __restrict__ X,
                                                   const bf16* __restrict__ WT,
                                                   const float* __restrict__ bias,
                                                   void* __restrict__ out, int epi) {
  __shared__ bf16 Xs[64][72];
  __shared__ bf16 Ws[64][72];
  int m0 = blockIdx.y * 64, n0 = blockIdx.x * 64;
  int tid = threadIdx.x, lane = tid & 63, wave = tid >> 6;
  int wm = wave >> 1, wn = wave & 1;
  int lr = lane & 15, lg = lane >> 4;
  f32x4 acc[2][2] = {};
  for (int k0 = 0; k0 < 512; k0 += 64) {
#pragma unroll
    for (int j = 0; j < 2; j++) {
      int cc = tid + 256 * j;
      int r = cc >> 3, c8 = (cc & 7) * 8;
      *(uint4*)&Xs[r][c8] = *(const uint4*)&X[(size_t)(m0 + r) * 512 + k0 + c8];
      *(uint4*)&Ws[r][c8] = *(const uint4*)&WT[(size_t)(n0 + r) * 512 + k0 + c8];
    }
    __syncthreads();
#pragma unroll
    for (int kk = 0; kk < 64; kk += 32) {
      bf16x8 a[2], b[2];
      a[0] = *(const bf16x8*)&Xs[wm * 32 + lr][kk + lg * 8];
      a[1] = *(const bf16x8*)&Xs[wm * 32 + 16 + lr][kk + lg * 8];
      b[0] = *(const bf16x8*)&Ws[wn * 32 + lr][kk + lg * 8];
      b[1] = *(const bf16x8*)&Ws[wn * 32 + 16 + lr][kk + lg * 8];
#pragma unroll
      for (int mi = 0; mi < 2; mi++)
#pragma unroll
        for (int ni = 0; ni < 2; ni++)
          acc[mi][ni] = __builtin_amdgcn_mfma_f32_16x16x32_bf16(a[mi], b[ni], acc[mi][ni], 0, 0, 0);
    }
    __syncthreads();
  }
#pragma unroll
  for (int mi = 0; mi < 2; mi++) {
#pragma unroll
    for (int ni = 0; ni < 2; ni++) {
#pragma unroll
      for (int i = 0; i < 4; i++) {
        int grow = m0 + wm * 32 + mi * 16 + lg * 4 + i;
        int gcol = n0 + wn * 32 + ni * 16 + lr;
        float v = acc[mi][ni][i];
        if (epi == 0) {
          int b = grow >> 11, q = grow & 2047, h = gcol >> 6, d = gcol & 63;
          ((bf16*)out)[((size_t)(b * NH + h) * NQ + q) * ND + d] = (bf16)(v * 0.125f);
        } else if (epi == 1 || epi == 2) {
          int b = grow >> 11, kq = grow & 2047, h = gcol >> 6, d = gcol & 63;
          ((bf16*)out)[((size_t)(b * NH + h) * NKK + kq) * ND + d] = (bf16)v;
        } else if (epi == 3) {
          v += bias[gcol];
          v = 1.0f / (1.0f + __expf(-v));
          ((float*)out)[(size_t)grow * 512 + gcol] = v;
        } else {
          ((float*)out)[(size_t)grow * 512 + gcol] = v + bias[gcol];
        }
      }
    }
  }
}

// ---------------- pass 1.5: vh[b][h][k][d] -> vT[b][h][d][k] ----------------
__global__ __launch_bounds__(256) void transpose_v_kernel(const bf16* __restrict__ vh,
                                                          bf16* __restrict__ vT) {
  __shared__ bf16 t[64][72];
  int bh = blockIdx.y;
  int kk0 = blockIdx.x * 64;
  const bf16* src = vh + (size_t)bh * NKK * ND;
  bf16* dst = vT + (size_t)bh * ND * NKK;
#pragma unroll
  for (int j = 0; j < 2; j++) {
    int c = threadIdx.x + 256 * j;
    int r = c >> 3, cc = (c & 7) * 8;
    *(uint4*)&t[r][cc] = *(const uint4*)&src[(size_t)(kk0 + r) * ND + cc];
  }
  __syncthreads();
#pragma unroll
  for (int j = 0; j < 2; j++) {
    int c = threadIdx.x + 256 * j;
    int d = c >> 3, ck = (c & 7) * 8;
    bf16 tmp[8];
#pragma unroll
    for (int x = 0; x < 8; x++) tmp[x] = t[ck + x][d];
    *(uint4*)&dst[(size_t)d * NKK + kk0 + ck] = *(const uint4*)tmp;
  }
}

// ---------------- global_load_lds helpers (compiler cannot sink these) ----------------
__device__ __forceinline__ void gload16(const float* g, float* l) {
  __builtin_amdgcn_global_load_lds((const __attribute__((address_space(1))) void*)g,
                                   (__attribute__((address_space(3))) void*)l, 16, 0, 0);
}
__device__ __forceinline__ void gload4(const float* g, float* l) {
  __builtin_amdgcn_global_load_lds((const __attribute__((address_space(1))) void*)g,
                                   (__attribute__((address_space(3))) void*)l, 4, 0, 0);
}

// ---------------- pass 2: fused flash attention (LDS-staged bias, 2-phase dbuf) ----------------
// grid 1024 (XCD-swizzled): (q-tile, b, split); 8 waves = 8 heads.
// Per 32-k chunk: stage next chunk's bias1/bias2 into LDS (global_load_lds),
// compute current chunk (bias from LDS, K/V vector loads from L2), barrier.
__global__ __launch_bounds__(512, 4) void attn_kernel(
    const bf16* __restrict__ qh, const bf16* __restrict__ kh, const bf16* __restrict__ vT,
    const float* __restrict__ bias1, const float* __restrict__ bias2,
    float* __restrict__ o_part, float* __restrict__ l_part) {
  __shared__ float b1s[2][16 * 32];        // [buf][row*32+col]            4 KB
  __shared__ float b2s[2][8 * 16 * 32];    // [buf][h*512+row*32+col]     32 KB
  __shared__ bf16 plds[8][16][PLS];        //                              9 KB
  // bijective XCD swizzle: 1024 WGs, 8 XCDs -> XCD x gets idx [x*128, x*128+128)
  // = all 128 q-tiles of one (b,split) combo (K/V stay L2-local per XCD).
  int l = blockIdx.x;
  int idx = (l & 7) * 128 + (l >> 3);
  int q0 = (idx & 127) * 16;
  int r = idx >> 7;
  int b = r & 1, split = r >> 1;
  int tid = threadIdx.x;
  int h = tid >> 6, lane = tid & 63;
  int lr = lane & 15, lg = lane >> 4;
  int kbase = split * KSPL;
  const bf16* Qp = qh + ((size_t)(b * NH + h) * NQ + q0) * ND;
  const bf16* Kp = kh + (size_t)(b * NH + h) * NKK * ND;
  const bf16* Vt = vT + (size_t)(b * NH + h) * ND * NKK;

  bf16x8 qf0 = *(const bf16x8*)&Qp[lr * 64 + lg * 8];
  bf16x8 qf1 = *(const bf16x8*)&Qp[lr * 64 + 32 + lg * 8];

  f32x4 o[4] = {};
  float lrow[4] = {0.f, 0.f, 0.f, 0.f};
  bf16(*pl)[PLS] = plds[h];

  // cooperative staging of one 32-k chunk's biases: b2 = 1024x16B, b1 = 512x4B
#define STAGE(c, s)                                                              \
  do {                                                                           \
    int kcol = kbase + (c) * 32;                                                 \
    _Pragma("unroll")                                                            \
    for (int j = 0; j < 2; j++) {                                                \
      int uu = tid + j * 512;                                                    \
      int h_ = uu >> 7, row_ = (uu >> 3) & 15, c4 = (uu & 7) * 4;                \
      gload16(bias2 + ((size_t)h_ * NQ + q0 + row_) * NKK + kcol + c4,           \
              &b2s[s][uu * 4]);                                                  \
    }                                                                            \
    int row1 = tid >> 5, col1 = tid & 31;                                        \
    gload4(bias1 + ((size_t)b * NQ + q0 + row1) * NKK + kcol + col1,             \
           &b1s[s][tid]);                                                        \
  } while (0)

  STAGE(0, 0);
  __syncthreads();

  for (int t = 0; t < NTILES; t++) {
    int s = t & 1;
    if (t + 1 < NTILES) STAGE(t + 1, s ^ 1);
    int k0 = kbase + t * 32;
    // V loads issued early; L2 latency covered by QK chain
    bf16x8 vf0 = *(const bf16x8*)&Vt[(size_t)(0 * 16 + lr) * NKK + k0 + lg * 8];
    bf16x8 vf1 = *(const bf16x8*)&Vt[(size_t)(1 * 16 + lr) * NKK + k0 + lg * 8];
    bf16x8 vf2 = *(const bf16x8*)&Vt[(size_t)(2 * 16 + lr) * NKK + k0 + lg * 8];
    bf16x8 vf3 = *(const bf16x8*)&Vt[(size_t)(3 * 16 + lr) * NKK + k0 + lg * 8];
    f32x4 sv[2];
#pragma unroll
    for (int f = 0; f < 2; f++) {
      const bf16* kp = Kp + (size_t)(k0 + f * 16 + lr) * ND + lg * 8;
      bf16x8 kfa = *(const bf16x8*)kp;
      bf16x8 kfb = *(const bf16x8*)(kp + 32);
      f32x4 c;
#pragma unroll
      for (int i = 0; i < 4; i++) {
        int off = (lg * 4 + i) * 32 + f * 16 + lr;
        c[i] = b1s[s][off] + b2s[s][h * 512 + off];
      }
      c = __builtin_amdgcn_mfma_f32_16x16x32_bf16(qf0, kfa, c, 0, 0, 0);
      c = __builtin_amdgcn_mfma_f32_16x16x32_bf16(qf1, kfb, c, 0, 0, 0);
      sv[f] = c;
    }
#pragma unroll
    for (int i = 0; i < 4; i++) {
      float p0 = __expf(sv[0][i]);
      float p1 = __expf(sv[1][i]);
      lrow[i] += p0 + p1;
      pl[lg * 4 + i][lr] = (bf16)p0;
      pl[lg * 4 + i][16 + lr] = (bf16)p1;
    }
    bf16x8 pa = *(const bf16x8*)&pl[lr][lg * 8];
    o[0] = __builtin_amdgcn_mfma_f32_16x16x32_bf16(pa, vf0, o[0], 0, 0, 0);
    o[1] = __builtin_amdgcn_mfma_f32_16x16x32_bf16(pa, vf1, o[1], 0, 0, 0);
    o[2] = __builtin_amdgcn_mfma_f32_16x16x32_bf16(pa, vf2, o[2], 0, 0, 0);
    o[3] = __builtin_amdgcn_mfma_f32_16x16x32_bf16(pa, vf3, o[3], 0, 0, 0);
    __syncthreads();  // drains staging vmcnt; buf s^1 ready for next iter
  }
#undef STAGE

  // final row-sum reduce over the 16 lanes holding this row's columns (lr bits only)
  float lred[4];
#pragma unroll
  for (int i = 0; i < 4; i++) {
    float L = lrow[i];
    L += __shfl_xor(L, 1);
    L += __shfl_xor(L, 2);
    L += __shfl_xor(L, 4);
    L += __shfl_xor(L, 8);
    lred[i] = L;
  }

  float* op = o_part + (((size_t)(split * NB + b) * NH + h) * NQ + q0) * ND;
#pragma unroll
  for (int ni = 0; ni < 4; ni++)
#pragma unroll
    for (int i = 0; i < 4; i++)
      op[(lg * 4 + i) * ND + ni * 16 + lr] = o[ni][i];
  if (lr == 0) {
    float* lp = l_part + ((size_t)(split * NB + b) * NH + h) * NQ + q0;
#pragma unroll
    for (int i = 0; i < 4; i++) lp[lg * 4 + i] = lred[i];
  }
}

// ---------------- pass 2b: combine splits, gate, -> bf16 ----------------
__global__ __launch_bounds__(256) void combine_kernel(const float* __restrict__ o_part,
                                                      const float* __restrict__ l_part,
                                                      const float* __restrict__ gate,
                                                      bf16* __restrict__ ao) {
  size_t t = (size_t)blockIdx.x * 256 + threadIdx.x;  // over B*Q*H*16
  int d0 = (int)(t & 15) * 4;
  int h = (int)((t >> 4) & 7);
  int q = (int)((t >> 7) & 2047);
  int b = (int)(t >> 18);
  f32x4 acc = {};
  float L = 0.f;
#pragma unroll
  for (int s = 0; s < SPLITS; s++) {
    size_t base = (((size_t)(s * NB + b) * NH + h) * NQ + q);
    acc += *(const f32x4*)&o_part[base * ND + d0];
    L += l_part[base];
  }
  float inv = 1.0f / L;
  size_t gi = ((size_t)b * NQ + q) * 512 + h * 64 + d0;
  f32x4 g = *(const f32x4*)&gate[gi];
  bf16x4 r;
#pragma unroll
  for (int j = 0; j < 4; j++) r[j] = (bf16)(acc[j] * inv * g[j]);
  *(bf16x4*)&ao[gi] = r;
}

// ---------------- host launch ----------------
extern "C" void kernel_launch(void* const* d_in, const int* in_sizes, int n_in,
                              void* d_out, int out_size, void* d_ws, size_t ws_size,
                              hipStream_t stream) {
  const float* query = (const float*)d_in[0];
  const float* keyd  = (const float*)d_in[1];
  const float* bias1 = (const float*)d_in[2];
  const float* bias2 = (const float*)d_in[3];
  const float* wq = (const float*)d_in[4];
  const float* wk = (const float*)d_in[5];
  const float* wv = (const float*)d_in[6];
  const float* wo = (const float*)d_in[7];
  const float* bo = (const float*)d_in[8];
  const float* wg = (const float*)d_in[9];
  const float* bg = (const float*)d_in[10];

  char* ws = (char*)d_ws;
  size_t off = 0;
  auto alloc = [&](size_t bytes) {
    void* p = ws + off;
    off += (bytes + 255) & ~(size_t)255;
    return p;
  };
  bf16* qd_bf = (bf16*)alloc((size_t)NM * 512 * 2);
  bf16* kd_bf = (bf16*)alloc((size_t)NM * 512 * 2);
  bf16* wqT = (bf16*)alloc((size_t)512 * 512 * 2);
  bf16* wkT = (bf16*)alloc((size_t)512 * 512 * 2);
  bf16* wvT = (bf16*)alloc((size_t)512 * 512 * 2);
  bf16* wgT = (bf16*)alloc((size_t)512 * 512 * 2);
  bf16* woT = (bf16*)alloc((size_t)512 * 512 * 2);
  bf16* qh  = (bf16*)alloc((size_t)NB * NH * NQ * ND * 2);
  bf16* kh  = (bf16*)alloc((size_t)NB * NH * NKK * ND * 2);
  bf16* vh  = (bf16*)alloc((size_t)NB * NH * NKK * ND * 2);
  bf16* vTt = (bf16*)alloc((size_t)NB * NH * ND * NKK * 2);
  float* gbuf = (float*)alloc((size_t)NM * 512 * 4);
  bf16* aob = (bf16*)alloc((size_t)NM * 512 * 2);
  float* o_part = (float*)alloc((size_t)SPLITS * NB * NH * NQ * ND * 4);
  float* l_part = (float*)alloc((size_t)SPLITS * NB * NH * NQ * 4);

  int n4 = NM * 512 / 4;
  cvt_bf16_kernel<<<dim3(n4 / 256), 256, 0, stream>>>(query, qd_bf, n4);
  cvt_bf16_kernel<<<dim3(n4 / 256), 256, 0, stream>>>(keyd, kd_bf, n4);

  transpose_w_kernel<<<dim3(16, 16), 256, 0, stream>>>(wq, wqT);
  transpose_w_kernel<<<dim3(16, 16), 256, 0, stream>>>(wk, wkT);
  transpose_w_kernel<<<dim3(16, 16), 256, 0, stream>>>(wv, wvT);
  transpose_w_kernel<<<dim3(16, 16), 256, 0, stream>>>(wg, wgT);
  transpose_w_kernel<<<dim3(16, 16), 256, 0, stream>>>(wo, woT);

  gemm_kernel<<<dim3(8, 64), 256, 0, stream>>>(qd_bf, wqT, nullptr, qh, 0);
  gemm_kernel<<<dim3(8, 64), 256, 0, stream>>>(kd_bf, wkT, nullptr, kh, 1);
  gemm_kernel<<<dim3(8, 64), 256, 0, stream>>>(kd_bf, wvT, nullptr, vh, 2);
  gemm_kernel<<<dim3(8, 64), 256, 0, stream>>>(qd_bf, wgT, bg, gbuf, 3);

  transpose_v_kernel<<<dim3(32, 16), 256, 0, stream>>>(vh, vTt);

  attn_kernel<<<dim3(1024), 512, 0, stream>>>(qh, kh, vTt, bias1, bias2, o_part, l_part);

  combine_kernel<<<dim3((NB * NQ * NH * 16) / 256), 256, 0, stream>>>(o_part, l_part, gbuf, aob);

  gemm_kernel<<<dim3(8, 64), 256, 0, stream>>>(aob, woT, bo, d_out, 4);
}